// Round 6
// baseline (791.526 us; speedup 1.0000x reference)
//
#include <hip/hip_runtime.h>

// Problem dims (fixed by setup_inputs)
#define Nn 200000
#define Dn 256
#define Hn 64
#define Sn 8
#define Mn 100000
#define Bn 4096

// Layer-1 tiling: block = 256 rows x 64 cols, 4 waves, each wave 64x64.
// Rows are pre-sorted by (s, batch); each block owns VB batches -> no global atomics.
#define RPB 256
#define KC 32
#define NT 256
#define VB 8      // batches per block (E[rows] = VB*M/B = 195)
#define XS 40     // LDS row stride in shorts (80B) -> conflict-free b128 frags
#define WS 40

#define NBIN (Sn * Bn)   // 32768 (s-major bins)

typedef __attribute__((ext_vector_type(8))) short bf16x8;   // MFMA A/B fragment
typedef __attribute__((ext_vector_type(4))) float f32x4;    // MFMA C/D fragment

// Truncation split: x ~= hi + lo (both bf16), packed pairwise into u32 lanes.
// err(hi+lo) ~ 2^-16 |x|; dropped lo*lo ~ 2^-16 -> fp32-grade via 3 MFMA products.
static __device__ __forceinline__ void split2(float a, float b,
                                              unsigned& h, unsigned& l) {
    unsigned ua = __float_as_uint(a), ub = __float_as_uint(b);
    unsigned ha = ua & 0xFFFF0000u, hb = ub & 0xFFFF0000u;
    float la = a - __uint_as_float(ha);
    float lb = b - __uint_as_float(hb);
    h = (ua >> 16) | hb;
    l = (__float_as_uint(la) >> 16) | (__float_as_uint(lb) & 0xFFFF0000u);
}

// ---------- prep: histogram of (s, batch) bins ----------
__global__ __launch_bounds__(256)
void hist_kernel(const int* __restrict__ sidx, const int* __restrict__ bidx,
                 unsigned* __restrict__ hist)
{
    const int s = blockIdx.y;
    const int m = blockIdx.x * 256 + threadIdx.x;
    if (m < Mn) {
        const int node = sidx[(size_t)s * Mn + m];
        const int sg   = bidx[node];
        atomicAdd(&hist[s * Bn + sg], 1u);
    }
}

// ---------- prep: exclusive scan over 32768 bins (single block) ----------
__global__ __launch_bounds__(1024)
void scan_kernel(const unsigned* __restrict__ hist, unsigned* __restrict__ bstart,
                 unsigned* __restrict__ cursor)
{
    __shared__ unsigned part[1024];
    const int tid  = threadIdx.x;
    const int base = tid * 32;
    unsigned vals[32], sum = 0;
#pragma unroll
    for (int j = 0; j < 32; ++j) { vals[j] = hist[base + j]; sum += vals[j]; }
    part[tid] = sum;
    __syncthreads();
    for (int d = 1; d < 1024; d <<= 1) {
        unsigned t = (tid >= d) ? part[tid - d] : 0u;
        __syncthreads();
        part[tid] += t;
        __syncthreads();
    }
    unsigned off = part[tid] - sum;   // exclusive offset of this thread's range
#pragma unroll
    for (int j = 0; j < 32; ++j) {
        bstart[base + j] = off;
        cursor[base + j] = off;
        off += vals[j];
    }
    if (tid == 1023) bstart[NBIN] = off;   // = S*M
}

// ---------- prep: scatter packed (seg<<18 | node) codes into bin order ----------
__global__ __launch_bounds__(256)
void scatter_kernel(const int* __restrict__ sidx, const int* __restrict__ bidx,
                    unsigned* __restrict__ cursor, unsigned* __restrict__ order)
{
    const int s = blockIdx.y;
    const int m = blockIdx.x * 256 + threadIdx.x;
    if (m < Mn) {
        const int node = sidx[(size_t)s * Mn + m];
        const int sg   = bidx[node];
        const unsigned pos = atomicAdd(&cursor[s * Bn + sg], 1u);
        order[pos] = ((unsigned)sg << 18) | (unsigned)node;   // sg<4096, node<2^18
    }
}

// ---------- layer 1: MFMA + LDS-local segment accumulation ----------
__global__ __launch_bounds__(NT, 3)
void l1_kernel(const float* __restrict__ nf, const float* __restrict__ W1,
               const float* __restrict__ b1, const unsigned* __restrict__ order,
               const unsigned* __restrict__ bstart, float* __restrict__ hsum)
{
    __shared__ __align__(16) unsigned short Xhi[RPB * XS];   // 20 KB
    __shared__ __align__(16) unsigned short Xlo[RPB * XS];   // 20 KB
    __shared__ __align__(16) unsigned short Whi[Hn * WS];    // 5 KB ([col][k])
    __shared__ __align__(16) unsigned short Wlo[Hn * WS];    // 5 KB
    __shared__ unsigned short rowlb[RPB];                    // 0.5 KB
    __shared__ float hacc[VB * Hn];                          // 2 KB

    const int s    = blockIdx.y;
    const int b0   = blockIdx.x * VB;
    const int tid  = threadIdx.x;
    const int lane = tid & 63;
    const int w    = tid >> 6;
    const int qq   = lane >> 4;
    const int r16  = lane & 15;
    const int wc   = tid & 63;   // W-staging col
    const int wq   = tid >> 6;   // W-staging k-oct

    const int bin0 = s * Bn + b0;
    const unsigned r0 = bstart[bin0];
    const unsigned r1 = bstart[bin0 + VB];

    if (tid < (VB * Hn) / 4)
        ((float4*)hacc)[tid] = make_float4(0.f, 0.f, 0.f, 0.f);

    // loop-invariant bias fragment (for the epilogue)
    float bcol[4];
#pragma unroll
    for (int ni = 0; ni < 4; ++ni) bcol[ni] = b1[s * Hn + 16 * ni + r16];

    const int nch = (int)((r1 - r0 + RPB - 1) / RPB);
    for (int ch = 0; ch < nch; ++ch) {
        const unsigned i  = r0 + (unsigned)ch * RPB + (unsigned)tid;
        const bool val    = (i < r1);
        const unsigned e  = val ? order[i] : 0u;
        const int node    = (int)(e & 0x3FFFFu);
        const int lb      = (int)(e >> 18) - b0;

        __syncthreads();   // previous chunk's epilogue fully done (rowlb reuse)
        rowlb[tid] = val ? (unsigned short)lb : (unsigned short)0xFFFF;

        const float* xrow = nf + (size_t)node * Dn;

        f32x4 acc[4][4];
#pragma unroll
        for (int mi = 0; mi < 4; ++mi)
#pragma unroll
            for (int ni = 0; ni < 4; ++ni) acc[mi][ni] = (f32x4){0.f, 0.f, 0.f, 0.f};

        float fx[32];   // prefetched own-row K-chunk
        float fw[8];    // prefetched W elems
        {
            const float4* xp = (const float4*)xrow;
#pragma unroll
            for (int v = 0; v < 8; ++v)
                *(float4*)&fx[4 * v] = val ? xp[v] : make_float4(0.f, 0.f, 0.f, 0.f);
            const float* wp = W1 + ((size_t)(s * Dn + 8 * wq)) * Hn + wc;
#pragma unroll
            for (int k = 0; k < 8; ++k) fw[k] = wp[(size_t)k * Hn];
        }

        for (int c = 0; c < Dn / KC; ++c) {
            __syncthreads();   // WAR on LDS planes

            // convert + store chunk c
#pragma unroll
            for (int v = 0; v < 4; ++v) {
                unsigned h[4], l[4];
#pragma unroll
                for (int j = 0; j < 4; ++j)
                    split2(fx[8 * v + 2 * j], fx[8 * v + 2 * j + 1], h[j], l[j]);
                *(uint4*)&Xhi[tid * XS + 8 * v] = make_uint4(h[0], h[1], h[2], h[3]);
                *(uint4*)&Xlo[tid * XS + 8 * v] = make_uint4(l[0], l[1], l[2], l[3]);
            }
            {
                unsigned h[4], l[4];
#pragma unroll
                for (int j = 0; j < 4; ++j) split2(fw[2 * j], fw[2 * j + 1], h[j], l[j]);
                *(uint4*)&Whi[wc * WS + 8 * wq] = make_uint4(h[0], h[1], h[2], h[3]);
                *(uint4*)&Wlo[wc * WS + 8 * wq] = make_uint4(l[0], l[1], l[2], l[3]);
            }
            __syncthreads();

            // prefetch chunk c+1 (overlaps MFMA phase)
            if (c + 1 < Dn / KC) {
                const int kk = (c + 1) * KC;
                const float4* xp = (const float4*)(xrow + kk);
#pragma unroll
                for (int v = 0; v < 8; ++v)
                    *(float4*)&fx[4 * v] = val ? xp[v] : make_float4(0.f, 0.f, 0.f, 0.f);
                const float* wp = W1 + ((size_t)(s * Dn + kk + 8 * wq)) * Hn + wc;
#pragma unroll
                for (int k = 0; k < 8; ++k) fw[k] = wp[(size_t)k * Hn];
            }

            // fragments + 48 MFMA
            bf16x8 ah[4], al[4];
#pragma unroll
            for (int mi = 0; mi < 4; ++mi) {
                const int rb = (64 * w + 16 * mi + r16) * XS + 8 * qq;
                ah[mi] = *(const bf16x8*)&Xhi[rb];
                al[mi] = *(const bf16x8*)&Xlo[rb];
            }
#pragma unroll
            for (int ni = 0; ni < 4; ++ni) {
                const int cb = (16 * ni + r16) * WS + 8 * qq;
                bf16x8 bh = *(const bf16x8*)&Whi[cb];
                bf16x8 bl = *(const bf16x8*)&Wlo[cb];
#pragma unroll
                for (int mi = 0; mi < 4; ++mi)
                    acc[mi][ni] = __builtin_amdgcn_mfma_f32_16x16x32_bf16(ah[mi], bh, acc[mi][ni], 0, 0, 0);
#pragma unroll
                for (int mi = 0; mi < 4; ++mi)
                    acc[mi][ni] = __builtin_amdgcn_mfma_f32_16x16x32_bf16(ah[mi], bl, acc[mi][ni], 0, 0, 0);
#pragma unroll
                for (int mi = 0; mi < 4; ++mi)
                    acc[mi][ni] = __builtin_amdgcn_mfma_f32_16x16x32_bf16(al[mi], bh, acc[mi][ni], 0, 0, 0);
            }
        }

        // epilogue: bias + relu + LDS-local segment accumulate
#pragma unroll
        for (int mi = 0; mi < 4; ++mi) {
#pragma unroll
            for (int r = 0; r < 4; ++r) {
                const int row = 64 * w + 16 * mi + 4 * qq + r;
                const int lb2 = rowlb[row];
                if (lb2 == 0xFFFF) continue;
#pragma unroll
                for (int ni = 0; ni < 4; ++ni) {
                    float v = fmaxf(acc[mi][ni][r] + bcol[ni], 0.f);
                    atomicAdd(&hacc[lb2 * Hn + 16 * ni + r16], v);
                }
            }
        }
    }

    __syncthreads();
    if (tid < (VB * Hn) / 4) {
        float4 v = ((float4*)hacc)[tid];
        ((float4*)(hsum + (size_t)bin0 * Hn))[tid] = v;
    }
}

// out[b][s*H+c] = sum_j hsum[s][b][j]*W2[s][j][c] + cnt(s,b)*b2[s][c]
__global__ __launch_bounds__(256)
void l2_kernel(const float* __restrict__ hsum, const unsigned* __restrict__ bstart,
               const float* __restrict__ W2, const float* __restrict__ b2,
               float* __restrict__ out)
{
    __shared__ float W2s[Hn * Hn];   // 16 KB
    const int s    = blockIdx.y;
    const int b0   = blockIdx.x * 64;
    const int tid  = threadIdx.x;
    const int lane = tid & 63;
    const int w    = tid >> 6;

    const float* w2g = W2 + (size_t)s * Hn * Hn;
#pragma unroll
    for (int i = 0; i < 4; ++i)
        ((float4*)W2s)[tid + 256 * i] = ((const float4*)w2g)[tid + 256 * i];
    __syncthreads();

    const float b2v = b2[s * Hn + lane];

#pragma unroll
    for (int g = 0; g < 4; ++g) {
        const int rb = b0 + w * 16 + g * 4;
        float hv[4], ct[4], acc[4];
#pragma unroll
        for (int i = 0; i < 4; ++i) {
            const int bin = s * Bn + rb + i;
            hv[i]  = hsum[(size_t)bin * Hn + lane];
            ct[i]  = (float)(bstart[bin + 1] - bstart[bin]);
            acc[i] = 0.f;
        }
#pragma unroll 8
        for (int j = 0; j < Hn; ++j) {
            float wv = W2s[j * Hn + lane];
#pragma unroll
            for (int i = 0; i < 4; ++i)
                acc[i] = fmaf(__shfl(hv[i], j), wv, acc[i]);
        }
#pragma unroll
        for (int i = 0; i < 4; ++i)
            out[(size_t)(rb + i) * (Sn * Hn) + s * Hn + lane] = acc[i] + ct[i] * b2v;
    }
}

extern "C" void kernel_launch(void* const* d_in, const int* in_sizes, int n_in,
                              void* d_out, int out_size, void* d_ws, size_t ws_size,
                              hipStream_t stream)
{
    const float* nf   = (const float*)d_in[0];  // node_features [N,D]
    const float* W1   = (const float*)d_in[1];  // [S,D,H]
    const float* b1   = (const float*)d_in[2];  // [S,H]
    const float* W2   = (const float*)d_in[3];  // [S,H,H]
    const float* b2   = (const float*)d_in[4];  // [S,H]
    const int*   sidx = (const int*)d_in[5];    // [S,M]
    const int*   bidx = (const int*)d_in[6];    // [N]
    float* out = (float*)d_out;

    // ws layout
    float*    hsum   = (float*)d_ws;                          // S*B*H f32 (8 MB)
    unsigned* hist   = (unsigned*)(hsum + (size_t)NBIN * Hn); // 32768 u32
    unsigned* bstart = hist + NBIN;                           // 32769 u32
    unsigned* cursor = bstart + NBIN + 1;                     // 32768 u32
    unsigned* order  = cursor + NBIN;                         // 800000 u32

    hipMemsetAsync(hist, 0, NBIN * sizeof(unsigned), stream);

    dim3 gm((Mn + 255) / 256, Sn);
    hist_kernel<<<gm, 256, 0, stream>>>(sidx, bidx, hist);
    scan_kernel<<<1, 1024, 0, stream>>>(hist, bstart, cursor);
    scatter_kernel<<<gm, 256, 0, stream>>>(sidx, bidx, cursor, order);

    dim3 g1(Bn / VB, Sn);   // 512 x 8
    l1_kernel<<<g1, NT, 0, stream>>>(nf, W1, b1, order, bstart, hsum);

    dim3 g2(Bn / 64, Sn);   // 64 x 8
    l2_kernel<<<g2, 256, 0, stream>>>(hsum, bstart, W2, b2, out);
}